// Round 27
// baseline (1791.572 us; speedup 1.0000x reference)
//
#include <hip/hip_runtime.h>

typedef unsigned short ushort_t;

#define NPTS 16384
#define CF 64
#define KCORR 2048

typedef __attribute__((ext_vector_type(8))) short bf16x8;
typedef __attribute__((ext_vector_type(4))) float f32x4;

__device__ __forceinline__ ushort_t f2bf(float f) {   // RNE
    union { float f; unsigned int i; } x; x.f = f;
    unsigned int u = x.i;
    u += 0x7FFFu + ((u >> 16) & 1);
    return (ushort_t)(u >> 16);
}

// ---------------------------------------------------------------------------
// fp32 arithmetic (bit-exact emulation targets) -- DO NOT TOUCH.
// ---------------------------------------------------------------------------
__device__ __forceinline__ float dot_avx2(const float* __restrict__ a,
                                          const float* __restrict__ b) {
#pragma clang fp contract(off)
    float v0 = 0.f, v1 = 0.f, v2 = 0.f, v3 = 0.f;
    float v4 = 0.f, v5 = 0.f, v6 = 0.f, v7 = 0.f;
    #pragma unroll
    for (int i = 0; i < CF; i += 8) {
        v0 = fmaf(a[i + 0], b[i + 0], v0);
        v1 = fmaf(a[i + 1], b[i + 1], v1);
        v2 = fmaf(a[i + 2], b[i + 2], v2);
        v3 = fmaf(a[i + 3], b[i + 3], v3);
        v4 = fmaf(a[i + 4], b[i + 4], v4);
        v5 = fmaf(a[i + 5], b[i + 5], v5);
        v6 = fmaf(a[i + 6], b[i + 6], v6);
        v7 = fmaf(a[i + 7], b[i + 7], v7);
    }
    float u0 = v0 + v4, u1 = v1 + v5, u2 = v2 + v6, u3 = v3 + v7;
    float t0 = u0 + u2, t1 = u1 + u3;
    return t0 + t1;
}

__device__ __forceinline__ float row_sumsq(const float* __restrict__ x) {
#pragma clang fp contract(off)
    float r[8];
    #pragma unroll
    for (int j = 0; j < 8; ++j) r[j] = x[j] * x[j];
    #pragma unroll
    for (int i = 8; i < 64; i += 8) {
        #pragma unroll
        for (int j = 0; j < 8; ++j) { float p = x[i + j] * x[i + j]; r[j] = r[j] + p; }
    }
    return ((r[0] + r[1]) + (r[2] + r[3])) + ((r[4] + r[5]) + (r[6] + r[7]));
}

// Selection dot: single accumulator, ascending k, fp32 FMA (r12-r26 exact).
__device__ __forceinline__ float dot_fma(const float* __restrict__ a,
                                         const float* __restrict__ b) {
    float acc = 0.0f;
    #pragma unroll
    for (int c = 0; c < CF; ++c) acc = fmaf(a[c], b[c], acc);
    return acc;
}

// ---------------------------------------------------------------------------
// conv: fp32 feats -> bf16 (RNE), both sides. One element per thread.
// ---------------------------------------------------------------------------
__global__ __launch_bounds__(256) void conv_kernel(
    const float* __restrict__ src_feats, const float* __restrict__ tgt_feats,
    ushort_t* __restrict__ sfb, ushort_t* __restrict__ tfb)
{
    int i = blockIdx.x * 256 + threadIdx.x;
    if (i >= NPTS * CF) return;
    sfb[i] = f2bf(src_feats[i]);
    tfb[i] = f2bf(tgt_feats[i]);
}

// ---------------------------------------------------------------------------
// prep: per-row sum of squares (fp32 pairwise). One thread per row.
// ---------------------------------------------------------------------------
__global__ __launch_bounds__(256) void prep_kernel(
    const float* __restrict__ src_feats, const float* __restrict__ tgt_feats,
    float* __restrict__ qq_src, float* __restrict__ qq_tgt)
{
    int t = blockIdx.x * 256 + threadIdx.x;
    if (t >= 2 * NPTS) return;
    const float* f = (t < NPTS) ? src_feats : tgt_feats;
    float*      qq = (t < NPTS) ? qq_src    : qq_tgt;
    int n = (t < NPTS) ? t : t - NPTS;
    float x[CF];
    #pragma unroll
    for (int c = 0; c < CF; c += 4) {
        float4 v = *(const float4*)(f + (size_t)n * CF + c);
        x[c] = v.x; x[c+1] = v.y; x[c+2] = v.z; x[c+3] = v.w;
    }
    qq[n] = row_sumsq(x);
}

// ---------------------------------------------------------------------------
// screen: MFMA bf16 pass -> per-query threshold T = (bf16 2nd-min d2) + 0.03.
// Error bound |d2_bf - d2_exact| <= ~0.008 for unit-norm rows, so the true
// exact top-2 provably satisfy d2_bf <= T. Values only, no index logic.
// Block = 256 thr = 4 waves; wave w owns 16 queries (cols); lane&15 = query,
// lane>>4 = k-group/row-group per m89/m97-verified fragment mappings.
// ---------------------------------------------------------------------------
__global__ __launch_bounds__(256) void screen_kernel(
    const ushort_t* __restrict__ sfb, const ushort_t* __restrict__ tfb,
    const float* __restrict__ qq_src, const float* __restrict__ qq_tgt,
    float* __restrict__ T)
{
    const int side = blockIdx.y;
    const int qb   = blockIdx.x;
    const int w    = threadIdx.x >> 6;
    const int lane = threadIdx.x & 63;

    const ushort_t* qfb = (side == 0) ? sfb : tfb;
    const ushort_t* cfb = (side == 0) ? tfb : sfb;
    const float*    qq  = (side == 0) ? qq_src : qq_tgt;
    const float*    ss  = (side == 0) ? qq_tgt : qq_src;

    const int qrow = qb * 64 + w * 16 + (lane & 15);
    const int kofs = (lane >> 4) * 8;

    bf16x8 bq0 = *(const bf16x8*)(qfb + (size_t)qrow * CF + kofs);
    bf16x8 bq1 = *(const bf16x8*)(qfb + (size_t)qrow * CF + 32 + kofs);
    const float qqn = qq[qrow];

    float m1 = 3.4e38f, m2 = 3.4e38f;

    #pragma unroll 2
    for (int tile = 0; tile < NPTS / 16; ++tile) {
        const int cbase = tile * 16;
        const ushort_t* cr = cfb + (size_t)(cbase + (lane & 15)) * CF + kofs;
        bf16x8 a0 = *(const bf16x8*)(cr);
        bf16x8 a1 = *(const bf16x8*)(cr + 32);
        f32x4 acc = {0.f, 0.f, 0.f, 0.f};
        acc = __builtin_amdgcn_mfma_f32_16x16x32_bf16(a0, bq0, acc, 0, 0, 0);
        acc = __builtin_amdgcn_mfma_f32_16x16x32_bf16(a1, bq1, acc, 0, 0, 0);
        const int rb = cbase + (lane >> 4) * 4;
        #pragma unroll
        for (int j = 0; j < 4; ++j) {
            float d2 = qqn - 2.0f * acc[j] + ss[rb + j];
            if (d2 < m2) { if (d2 < m1) { m2 = m1; m1 = d2; } else m2 = d2; }
        }
    }

    // merge top2 values across the 4 row-groups (lanes sharing lane&15)
    #pragma unroll
    for (int off = 16; off <= 32; off <<= 1) {
        float o1 = __shfl_xor(m1, off, 64);
        float o2 = __shfl_xor(m2, off, 64);
        float n1 = fminf(m1, o1);
        float n2 = fminf(fmaxf(m1, o1), fminf(m2, o2));
        m1 = n1; m2 = n2;
    }
    if (lane < 16) T[(size_t)side * NPTS + qrow] = m2 + 0.03f;
}

// ---------------------------------------------------------------------------
// refine: MFMA bf16 pass again; candidates with d2_bf <= T get the EXACT
// fp32 evaluation (dot_fma ascending chain + 3-op contract-off d2 -- the
// r12-r26 bit-exact arithmetic) and lexicographic (d,idx) top-2 tracking.
// Survivors ~2-4/query -> exact work is negligible. Output: global top-2.
// ---------------------------------------------------------------------------
__global__ __launch_bounds__(256) void refine_kernel(
    const ushort_t* __restrict__ sfb, const ushort_t* __restrict__ tfb,
    const float* __restrict__ src_feats, const float* __restrict__ tgt_feats,
    const float* __restrict__ qq_src, const float* __restrict__ qq_tgt,
    const float* __restrict__ T,
    float* __restrict__ pd0, float* __restrict__ pd1,
    int* __restrict__ pi0, int* __restrict__ pi1)
{
    const int side = blockIdx.y;
    const int qb   = blockIdx.x;
    const int w    = threadIdx.x >> 6;
    const int lane = threadIdx.x & 63;

    const ushort_t* qfb = (side == 0) ? sfb : tfb;
    const ushort_t* cfb = (side == 0) ? tfb : sfb;
    const float*    qf  = (side == 0) ? src_feats : tgt_feats;
    const float*    cf  = (side == 0) ? tgt_feats : src_feats;
    const float*    qq  = (side == 0) ? qq_src : qq_tgt;
    const float*    ss  = (side == 0) ? qq_tgt : qq_src;

    const int qrow = qb * 64 + w * 16 + (lane & 15);
    const int kofs = (lane >> 4) * 8;

    bf16x8 bq0 = *(const bf16x8*)(qfb + (size_t)qrow * CF + kofs);
    bf16x8 bq1 = *(const bf16x8*)(qfb + (size_t)qrow * CF + 32 + kofs);
    const float qqn = qq[qrow];
    const float Tq  = T[(size_t)side * NPTS + qrow];
    const float* qp = qf + (size_t)qrow * CF;

    float rd0 = 3.4e38f, rd1 = 3.4e38f;
    int   ri0 = 0x7fffffff, ri1 = 0x7fffffff;

    #pragma unroll 2
    for (int tile = 0; tile < NPTS / 16; ++tile) {
        const int cbase = tile * 16;
        const ushort_t* cr = cfb + (size_t)(cbase + (lane & 15)) * CF + kofs;
        bf16x8 a0 = *(const bf16x8*)(cr);
        bf16x8 a1 = *(const bf16x8*)(cr + 32);
        f32x4 acc = {0.f, 0.f, 0.f, 0.f};
        acc = __builtin_amdgcn_mfma_f32_16x16x32_bf16(a0, bq0, acc, 0, 0, 0);
        acc = __builtin_amdgcn_mfma_f32_16x16x32_bf16(a1, bq1, acc, 0, 0, 0);
        const int rb = cbase + (lane >> 4) * 4;
        #pragma unroll
        for (int j = 0; j < 4; ++j) {
            float d2b = qqn - 2.0f * acc[j] + ss[rb + j];
            if (d2b <= Tq) {
                int cand = rb + j;
                float dote = dot_fma(qp, cf + (size_t)cand * CF);
                float d2e;
                {
#pragma clang fp contract(off)
                    float twod = 2.0f * dote;     // exact
                    float t1v  = qqn - twod;      // one RNE round
                    d2e = t1v + ss[cand];         // one RNE round
                }
                if (d2e < rd1 || (d2e == rd1 && cand < ri1)) {
                    if (d2e < rd0 || (d2e == rd0 && cand < ri0)) {
                        rd1 = rd0; ri1 = ri0; rd0 = d2e; ri0 = cand;
                    } else { rd1 = d2e; ri1 = cand; }
                }
            }
        }
    }

    // lexicographic (d,i) top-2 merge across the 4 row-groups
    #pragma unroll
    for (int off = 16; off <= 32; off <<= 1) {
        float od0 = __shfl_xor(rd0, off, 64);
        float od1 = __shfl_xor(rd1, off, 64);
        int   oi0 = __shfl_xor(ri0, off, 64);
        int   oi1 = __shfl_xor(ri1, off, 64);
        bool aw = (rd0 < od0) || (rd0 == od0 && ri0 < oi0);
        float w1d = aw ? rd0 : od0;  int w1i = aw ? ri0 : oi0;
        float l1d = aw ? od0 : rd0;  int l1i = aw ? oi0 : ri0;  // loser of firsts
        float s1d = aw ? rd1 : od1;  int s1i = aw ? ri1 : oi1;  // winner's 2nd
        bool bw = (s1d < l1d) || (s1d == l1d && s1i < l1i);
        float w2d = bw ? s1d : l1d;  int w2i = bw ? s1i : l1i;
        rd0 = w1d; ri0 = w1i; rd1 = w2d; ri1 = w2i;
    }

    if (lane < 16) {
        size_t slot = (size_t)side * NPTS + qrow;
        pd0[slot] = rd0; pd1[slot] = rd1;
        pi0[slot] = ri0; pi1[slot] = ri1;
    }
}

// ---------------------------------------------------------------------------
// merge: single-slot partials -> sims via dot_avx2, weight in strict fp32.
// ---------------------------------------------------------------------------
__global__ __launch_bounds__(256) void merge_kernel(
    const float* __restrict__ src_feats, const float* __restrict__ tgt_feats,
    const float* __restrict__ pd0, const float* __restrict__ pd1,
    const int* __restrict__ pi0, const int* __restrict__ pi1,
    float* __restrict__ wgt, int* __restrict__ bidx)
{
    int t = blockIdx.x * blockDim.x + threadIdx.x;
    if (t >= 2 * NPTS) return;
    int side = t >> 14, n = t & (NPTS - 1);

    size_t slot = (size_t)side * NPTS + n;
    int i0 = pi0[slot], i1 = pi1[slot];
    (void)pd0; (void)pd1;
    if (i0 < 0 || i0 >= NPTS) i0 = 0;
    if (i1 < 0 || i1 >= NPTS) i1 = 0;

    const float* qf = (side == 0) ? src_feats : tgt_feats;
    const float* sf = (side == 0) ? tgt_feats : src_feats;

    float q[CF];
    #pragma unroll
    for (int c = 0; c < CF; c += 4) {
        float4 v = *(const float4*)(qf + (size_t)n * CF + c);
        q[c] = v.x; q[c+1] = v.y; q[c+2] = v.z; q[c+3] = v.w;
    }

    float dotA = dot_avx2(sf + (size_t)i0 * CF, q);
    float dotB = dot_avx2(sf + (size_t)i1 * CF, q);

    float w;
    {
#pragma clang fp contract(off)
        float sim0 = 1.0f - dotA;
        float sim1 = 1.0f - dotB;
        float den  = sim1 + 1e-8f;
        w = 1.0f - sim0 / den;
    }
    wgt[t]  = w;
    bidx[t] = i0;
}

// ---------------------------------------------------------------------------
// rank + gather (unchanged from the passing rounds)
// ---------------------------------------------------------------------------
__global__ __launch_bounds__(256) void rank_gather_kernel(
    const float* __restrict__ wgt, const int* __restrict__ bidx,
    const float* __restrict__ src_points, const float* __restrict__ tgt_points,
    const float* __restrict__ src_feats,  const float* __restrict__ tgt_feats,
    float* __restrict__ out)
{
    const int side = blockIdx.y;
    const int n = blockIdx.x * 256 + threadIdx.x;
    const float* w = wgt + (size_t)side * NPTS;
    const float wn = w[n];

    __shared__ float tile[4096];
    int cnt = 0;
    for (int t0 = 0; t0 < NPTS; t0 += 4096) {
        __syncthreads();
        for (int j = threadIdx.x; j < 4096; j += 256) tile[j] = w[t0 + j];
        __syncthreads();
        #pragma unroll 8
        for (int j = 0; j < 4096; ++j) {
            float wj = tile[j];
            int jj = t0 + j;
            cnt += (wj > wn) || (wj == wn && jj < n);
        }
    }

    if (cnt < KCORR) {
        int r = side * KCORR + cnt;
        int sidx = bidx[(size_t)side * NPTS + n];
        if (sidx < 0) sidx = 0;
        int src_row = (side == 0) ? n : sidx;
        int tgt_row = (side == 0) ? sidx : n;

        float* out_srcP = out;                          // [2K,3]
        float* out_tgtP = out + 2 * KCORR * 3;          // [2K,3]
        float* out_srcF = out + 4 * KCORR * 3;          // [2K,64]
        float* out_tgtF = out_srcF + 2 * KCORR * CF;    // [2K,64]
        float* out_w    = out_tgtF + 2 * KCORR * CF;    // [2K]

        #pragma unroll
        for (int k = 0; k < 3; ++k) {
            out_srcP[(size_t)r * 3 + k] = src_points[(size_t)src_row * 3 + k];
            out_tgtP[(size_t)r * 3 + k] = tgt_points[(size_t)tgt_row * 3 + k];
        }
        const float4* sfr = (const float4*)(src_feats + (size_t)src_row * CF);
        const float4* tfr = (const float4*)(tgt_feats + (size_t)tgt_row * CF);
        float4* so = (float4*)(out_srcF + (size_t)r * CF);
        float4* to = (float4*)(out_tgtF + (size_t)r * CF);
        #pragma unroll
        for (int c = 0; c < CF / 4; ++c) { so[c] = sfr[c]; to[c] = tfr[c]; }
        out_w[r] = wn;
    }
}

// ---------------------------------------------------------------------------
extern "C" void kernel_launch(void* const* d_in, const int* in_sizes, int n_in,
                              void* d_out, int out_size, void* d_ws, size_t ws_size,
                              hipStream_t stream)
{
    const float* src_points = (const float*)d_in[0];
    const float* tgt_points = (const float*)d_in[1];
    const float* src_feats  = (const float*)d_in[2];
    const float* tgt_feats  = (const float*)d_in[3];
    float* out = (float*)d_out;
    (void)in_sizes; (void)n_in; (void)out_size; (void)ws_size;

    char* ws = (char*)d_ws;
    size_t off = 0;
    auto alloc = [&](size_t bytes) -> void* {
        void* p = ws + off;
        off += (bytes + 255) & ~(size_t)255;
        return p;
    };
    ushort_t* sfb = (ushort_t*)alloc(sizeof(ushort_t) * (size_t)NPTS * CF);
    ushort_t* tfb = (ushort_t*)alloc(sizeof(ushort_t) * (size_t)NPTS * CF);
    float* qq_src = (float*)alloc(sizeof(float) * NPTS);
    float* qq_tgt = (float*)alloc(sizeof(float) * NPTS);
    float* T      = (float*)alloc(sizeof(float) * 2 * NPTS);
    float* wgt    = (float*)alloc(sizeof(float) * 2 * NPTS);
    int*   bidx   = (int*)alloc(sizeof(int) * 2 * NPTS);
    float* pd0    = (float*)alloc(sizeof(float) * 2 * NPTS);
    float* pd1    = (float*)alloc(sizeof(float) * 2 * NPTS);
    int*   pi0    = (int*)alloc(sizeof(int) * 2 * NPTS);
    int*   pi1    = (int*)alloc(sizeof(int) * 2 * NPTS);

    conv_kernel<<<(NPTS * CF + 255) / 256, 256, 0, stream>>>(
        src_feats, tgt_feats, sfb, tfb);

    prep_kernel<<<(2 * NPTS + 255) / 256, 256, 0, stream>>>(
        src_feats, tgt_feats, qq_src, qq_tgt);

    screen_kernel<<<dim3(NPTS / 64, 2), 256, 0, stream>>>(
        sfb, tfb, qq_src, qq_tgt, T);

    refine_kernel<<<dim3(NPTS / 64, 2), 256, 0, stream>>>(
        sfb, tfb, src_feats, tgt_feats, qq_src, qq_tgt, T,
        pd0, pd1, pi0, pi1);

    merge_kernel<<<(2 * NPTS + 255) / 256, 256, 0, stream>>>(
        src_feats, tgt_feats, pd0, pd1, pi0, pi1, wgt, bidx);

    rank_gather_kernel<<<dim3(NPTS / 256, 2), 256, 0, stream>>>(
        wgt, bidx, src_points, tgt_points, src_feats, tgt_feats, out);
}

// Round 28
// 1618.665 us; speedup vs baseline: 1.1068x; 1.1068x over previous
//
#include <hip/hip_runtime.h>

typedef unsigned short ushort_t;

#define NPTS 16384
#define CF 64
#define KCORR 2048
#define NCH 4
#define CHSZ (NPTS / NCH)

typedef __attribute__((ext_vector_type(8))) short bf16x8;
typedef __attribute__((ext_vector_type(4))) float f32x4;

__device__ __forceinline__ ushort_t f2bf(float f) {   // RNE
    union { float f; unsigned int i; } x; x.f = f;
    unsigned int u = x.i;
    u += 0x7FFFu + ((u >> 16) & 1);
    return (ushort_t)(u >> 16);
}

// ---------------------------------------------------------------------------
// fp32 arithmetic (bit-exact emulation targets) -- DO NOT TOUCH.
// ---------------------------------------------------------------------------
__device__ __forceinline__ float dot_avx2(const float* __restrict__ a,
                                          const float* __restrict__ b) {
#pragma clang fp contract(off)
    float v0 = 0.f, v1 = 0.f, v2 = 0.f, v3 = 0.f;
    float v4 = 0.f, v5 = 0.f, v6 = 0.f, v7 = 0.f;
    #pragma unroll
    for (int i = 0; i < CF; i += 8) {
        v0 = fmaf(a[i + 0], b[i + 0], v0);
        v1 = fmaf(a[i + 1], b[i + 1], v1);
        v2 = fmaf(a[i + 2], b[i + 2], v2);
        v3 = fmaf(a[i + 3], b[i + 3], v3);
        v4 = fmaf(a[i + 4], b[i + 4], v4);
        v5 = fmaf(a[i + 5], b[i + 5], v5);
        v6 = fmaf(a[i + 6], b[i + 6], v6);
        v7 = fmaf(a[i + 7], b[i + 7], v7);
    }
    float u0 = v0 + v4, u1 = v1 + v5, u2 = v2 + v6, u3 = v3 + v7;
    float t0 = u0 + u2, t1 = u1 + u3;
    return t0 + t1;
}

__device__ __forceinline__ float row_sumsq(const float* __restrict__ x) {
#pragma clang fp contract(off)
    float r[8];
    #pragma unroll
    for (int j = 0; j < 8; ++j) r[j] = x[j] * x[j];
    #pragma unroll
    for (int i = 8; i < 64; i += 8) {
        #pragma unroll
        for (int j = 0; j < 8; ++j) { float p = x[i + j] * x[i + j]; r[j] = r[j] + p; }
    }
    return ((r[0] + r[1]) + (r[2] + r[3])) + ((r[4] + r[5]) + (r[6] + r[7]));
}

// Selection dot: single accumulator, ascending k, fp32 FMA (r12-r27 exact).
__device__ __forceinline__ float dot_fma(const float* __restrict__ a,
                                         const float* __restrict__ b) {
    float acc = 0.0f;
    #pragma unroll
    for (int c = 0; c < CF; ++c) acc = fmaf(a[c], b[c], acc);
    return acc;
}

// ---------------------------------------------------------------------------
// conv: fp32 feats -> bf16 (RNE), both sides.
// ---------------------------------------------------------------------------
__global__ __launch_bounds__(256) void conv_kernel(
    const float* __restrict__ src_feats, const float* __restrict__ tgt_feats,
    ushort_t* __restrict__ sfb, ushort_t* __restrict__ tfb)
{
    int i = blockIdx.x * 256 + threadIdx.x;
    if (i >= NPTS * CF) return;
    sfb[i] = f2bf(src_feats[i]);
    tfb[i] = f2bf(tgt_feats[i]);
}

// ---------------------------------------------------------------------------
// prep: per-row sum of squares (fp32 pairwise). One thread per row.
// ---------------------------------------------------------------------------
__global__ __launch_bounds__(256) void prep_kernel(
    const float* __restrict__ src_feats, const float* __restrict__ tgt_feats,
    float* __restrict__ qq_src, float* __restrict__ qq_tgt)
{
    int t = blockIdx.x * 256 + threadIdx.x;
    if (t >= 2 * NPTS) return;
    const float* f = (t < NPTS) ? src_feats : tgt_feats;
    float*      qq = (t < NPTS) ? qq_src    : qq_tgt;
    int n = (t < NPTS) ? t : t - NPTS;
    float x[CF];
    #pragma unroll
    for (int c = 0; c < CF; c += 4) {
        float4 v = *(const float4*)(f + (size_t)n * CF + c);
        x[c] = v.x; x[c+1] = v.y; x[c+2] = v.z; x[c+3] = v.w;
    }
    qq[n] = row_sumsq(x);
}

// ---------------------------------------------------------------------------
// screen: MFMA bf16 pass over ONE candidate chunk -> per-(query,chunk)
// min-2 of d2_bf. Pure mins, so the chunk-combined T equals r27's exactly.
// Wave layout (m89/m97-verified): lane&15 = query col, lane>>4 = row/k-group.
// ---------------------------------------------------------------------------
__global__ __launch_bounds__(256) void screen_kernel(
    const ushort_t* __restrict__ sfb, const ushort_t* __restrict__ tfb,
    const float* __restrict__ qq_src, const float* __restrict__ qq_tgt,
    float* __restrict__ pm1, float* __restrict__ pm2)
{
    const int side = blockIdx.z;
    const int ch   = blockIdx.y;
    const int qb   = blockIdx.x;
    const int w    = threadIdx.x >> 6;
    const int lane = threadIdx.x & 63;

    const ushort_t* qfb = (side == 0) ? sfb : tfb;
    const ushort_t* cfb = (side == 0) ? tfb : sfb;
    const float*    qq  = (side == 0) ? qq_src : qq_tgt;
    const float*    ss  = (side == 0) ? qq_tgt : qq_src;

    const int qrow = qb * 64 + w * 16 + (lane & 15);
    const int kofs = (lane >> 4) * 8;

    bf16x8 bq0 = *(const bf16x8*)(qfb + (size_t)qrow * CF + kofs);
    bf16x8 bq1 = *(const bf16x8*)(qfb + (size_t)qrow * CF + 32 + kofs);
    const float qqn = qq[qrow];

    float m1 = 3.4e38f, m2 = 3.4e38f;

    const int t0 = ch * (CHSZ / 16);
    #pragma unroll 2
    for (int tile = t0; tile < t0 + CHSZ / 16; ++tile) {
        const int cbase = tile * 16;
        const ushort_t* cr = cfb + (size_t)(cbase + (lane & 15)) * CF + kofs;
        bf16x8 a0 = *(const bf16x8*)(cr);
        bf16x8 a1 = *(const bf16x8*)(cr + 32);
        f32x4 acc = {0.f, 0.f, 0.f, 0.f};
        acc = __builtin_amdgcn_mfma_f32_16x16x32_bf16(a0, bq0, acc, 0, 0, 0);
        acc = __builtin_amdgcn_mfma_f32_16x16x32_bf16(a1, bq1, acc, 0, 0, 0);
        const int rb = cbase + (lane >> 4) * 4;
        #pragma unroll
        for (int j = 0; j < 4; ++j) {
            float d2 = qqn - 2.0f * acc[j] + ss[rb + j];
            if (d2 < m2) { if (d2 < m1) { m2 = m1; m1 = d2; } else m2 = d2; }
        }
    }

    #pragma unroll
    for (int off = 16; off <= 32; off <<= 1) {
        float o1 = __shfl_xor(m1, off, 64);
        float o2 = __shfl_xor(m2, off, 64);
        float n1 = fminf(m1, o1);
        float n2 = fminf(fmaxf(m1, o1), fminf(m2, o2));
        m1 = n1; m2 = n2;
    }
    if (lane < 16) {
        size_t slot = ((size_t)side * NCH + ch) * NPTS + qrow;
        pm1[slot] = m1; pm2[slot] = m2;
    }
}

// ---------------------------------------------------------------------------
// combineT: min-merge the NCH chunk (m1,m2) pairs -> T = global m2 + margin.
// ---------------------------------------------------------------------------
__global__ __launch_bounds__(256) void combineT_kernel(
    const float* __restrict__ pm1, const float* __restrict__ pm2,
    float* __restrict__ T)
{
    int t = blockIdx.x * 256 + threadIdx.x;
    if (t >= 2 * NPTS) return;
    int side = t >> 14, n = t & (NPTS - 1);
    float m1 = 3.4e38f, m2 = 3.4e38f;
    for (int ch = 0; ch < NCH; ++ch) {
        size_t slot = ((size_t)side * NCH + ch) * NPTS + n;
        float o1 = pm1[slot], o2 = pm2[slot];
        float n1 = fminf(m1, o1);
        float n2 = fminf(fmaxf(m1, o1), fminf(m2, o2));
        m1 = n1; m2 = n2;
    }
    T[t] = m2 + 0.03f;
}

// ---------------------------------------------------------------------------
// refine: MFMA pass over ONE chunk; survivors (d2_bf <= T) get the EXACT
// fp32 evaluation (r12-r27 arithmetic) with lexicographic (d,idx) top-2.
// Per-chunk output; lex merge across chunks == global top-2 (total order).
// ---------------------------------------------------------------------------
__global__ __launch_bounds__(256) void refine_kernel(
    const ushort_t* __restrict__ sfb, const ushort_t* __restrict__ tfb,
    const float* __restrict__ src_feats, const float* __restrict__ tgt_feats,
    const float* __restrict__ qq_src, const float* __restrict__ qq_tgt,
    const float* __restrict__ T,
    float* __restrict__ pd0, float* __restrict__ pd1,
    int* __restrict__ pi0, int* __restrict__ pi1)
{
    const int side = blockIdx.z;
    const int ch   = blockIdx.y;
    const int qb   = blockIdx.x;
    const int w    = threadIdx.x >> 6;
    const int lane = threadIdx.x & 63;

    const ushort_t* qfb = (side == 0) ? sfb : tfb;
    const ushort_t* cfb = (side == 0) ? tfb : sfb;
    const float*    qf  = (side == 0) ? src_feats : tgt_feats;
    const float*    cf  = (side == 0) ? tgt_feats : src_feats;
    const float*    qq  = (side == 0) ? qq_src : qq_tgt;
    const float*    ss  = (side == 0) ? qq_tgt : qq_src;

    const int qrow = qb * 64 + w * 16 + (lane & 15);
    const int kofs = (lane >> 4) * 8;

    bf16x8 bq0 = *(const bf16x8*)(qfb + (size_t)qrow * CF + kofs);
    bf16x8 bq1 = *(const bf16x8*)(qfb + (size_t)qrow * CF + 32 + kofs);
    const float qqn = qq[qrow];
    const float Tq  = T[(size_t)side * NPTS + qrow];
    const float* qp = qf + (size_t)qrow * CF;

    float rd0 = 3.4e38f, rd1 = 3.4e38f;
    int   ri0 = 0x7fffffff, ri1 = 0x7fffffff;

    const int t0 = ch * (CHSZ / 16);
    #pragma unroll 2
    for (int tile = t0; tile < t0 + CHSZ / 16; ++tile) {
        const int cbase = tile * 16;
        const ushort_t* cr = cfb + (size_t)(cbase + (lane & 15)) * CF + kofs;
        bf16x8 a0 = *(const bf16x8*)(cr);
        bf16x8 a1 = *(const bf16x8*)(cr + 32);
        f32x4 acc = {0.f, 0.f, 0.f, 0.f};
        acc = __builtin_amdgcn_mfma_f32_16x16x32_bf16(a0, bq0, acc, 0, 0, 0);
        acc = __builtin_amdgcn_mfma_f32_16x16x32_bf16(a1, bq1, acc, 0, 0, 0);
        const int rb = cbase + (lane >> 4) * 4;
        #pragma unroll
        for (int j = 0; j < 4; ++j) {
            float d2b = qqn - 2.0f * acc[j] + ss[rb + j];
            if (d2b <= Tq) {
                int cand = rb + j;
                float dote = dot_fma(qp, cf + (size_t)cand * CF);
                float d2e;
                {
#pragma clang fp contract(off)
                    float twod = 2.0f * dote;     // exact
                    float t1v  = qqn - twod;      // one RNE round
                    d2e = t1v + ss[cand];         // one RNE round
                }
                if (d2e < rd1 || (d2e == rd1 && cand < ri1)) {
                    if (d2e < rd0 || (d2e == rd0 && cand < ri0)) {
                        rd1 = rd0; ri1 = ri0; rd0 = d2e; ri0 = cand;
                    } else { rd1 = d2e; ri1 = cand; }
                }
            }
        }
    }

    // lexicographic (d,i) top-2 merge across the 4 row-groups
    #pragma unroll
    for (int off = 16; off <= 32; off <<= 1) {
        float od0 = __shfl_xor(rd0, off, 64);
        float od1 = __shfl_xor(rd1, off, 64);
        int   oi0 = __shfl_xor(ri0, off, 64);
        int   oi1 = __shfl_xor(ri1, off, 64);
        bool aw = (rd0 < od0) || (rd0 == od0 && ri0 < oi0);
        float w1d = aw ? rd0 : od0;  int w1i = aw ? ri0 : oi0;
        float l1d = aw ? od0 : rd0;  int l1i = aw ? oi0 : ri0;
        float s1d = aw ? rd1 : od1;  int s1i = aw ? ri1 : oi1;
        bool bw = (s1d < l1d) || (s1d == l1d && s1i < l1i);
        float w2d = bw ? s1d : l1d;  int w2i = bw ? s1i : l1i;
        rd0 = w1d; ri0 = w1i; rd1 = w2d; ri1 = w2i;
    }

    if (lane < 16) {
        size_t slot = ((size_t)side * NCH + ch) * NPTS + qrow;
        pd0[slot] = rd0; pd1[slot] = rd1;
        pi0[slot] = ri0; pi1[slot] = ri1;
    }
}

// ---------------------------------------------------------------------------
// merge: lex-(d,i) merge of NCH chunk top-2s -> global top-2 (== r12-r27
// selection); sims via dot_avx2, weight in strict fp32.
// ---------------------------------------------------------------------------
__global__ __launch_bounds__(256) void merge_kernel(
    const float* __restrict__ src_feats, const float* __restrict__ tgt_feats,
    const float* __restrict__ pd0, const float* __restrict__ pd1,
    const int* __restrict__ pi0, const int* __restrict__ pi1,
    float* __restrict__ wgt, int* __restrict__ bidx)
{
    int t = blockIdx.x * blockDim.x + threadIdx.x;
    if (t >= 2 * NPTS) return;
    int side = t >> 14, n = t & (NPTS - 1);

    float d0 = 3.4e38f, d1 = 3.4e38f;
    int   i0 = 0x7fffffff, i1 = 0x7fffffff;
    for (int ch = 0; ch < NCH; ++ch) {
        size_t slot = ((size_t)side * NCH + ch) * NPTS + n;
        float cd[2] = { pd0[slot], pd1[slot] };
        int   ci[2] = { pi0[slot], pi1[slot] };
        #pragma unroll
        for (int k = 0; k < 2; ++k) {
            float d = cd[k]; int i = ci[k];
            if (d < d1 || (d == d1 && i < i1)) {
                if (d < d0 || (d == d0 && i < i0)) {
                    d1 = d0; i1 = i0; d0 = d; i0 = i;
                } else { d1 = d; i1 = i; }
            }
        }
    }
    if (i0 < 0 || i0 >= NPTS) i0 = 0;
    if (i1 < 0 || i1 >= NPTS) i1 = 0;

    const float* qf = (side == 0) ? src_feats : tgt_feats;
    const float* sf = (side == 0) ? tgt_feats : src_feats;

    float q[CF];
    #pragma unroll
    for (int c = 0; c < CF; c += 4) {
        float4 v = *(const float4*)(qf + (size_t)n * CF + c);
        q[c] = v.x; q[c+1] = v.y; q[c+2] = v.z; q[c+3] = v.w;
    }

    float dotA = dot_avx2(sf + (size_t)i0 * CF, q);
    float dotB = dot_avx2(sf + (size_t)i1 * CF, q);

    float w;
    {
#pragma clang fp contract(off)
        float sim0 = 1.0f - dotA;
        float sim1 = 1.0f - dotB;
        float den  = sim1 + 1e-8f;
        w = 1.0f - sim0 / den;
    }
    wgt[t]  = w;
    bidx[t] = i0;
}

// ---------------------------------------------------------------------------
// rank + gather (unchanged from the passing rounds)
// ---------------------------------------------------------------------------
__global__ __launch_bounds__(256) void rank_gather_kernel(
    const float* __restrict__ wgt, const int* __restrict__ bidx,
    const float* __restrict__ src_points, const float* __restrict__ tgt_points,
    const float* __restrict__ src_feats,  const float* __restrict__ tgt_feats,
    float* __restrict__ out)
{
    const int side = blockIdx.y;
    const int n = blockIdx.x * 256 + threadIdx.x;
    const float* w = wgt + (size_t)side * NPTS;
    const float wn = w[n];

    __shared__ float tile[4096];
    int cnt = 0;
    for (int t0 = 0; t0 < NPTS; t0 += 4096) {
        __syncthreads();
        for (int j = threadIdx.x; j < 4096; j += 256) tile[j] = w[t0 + j];
        __syncthreads();
        #pragma unroll 8
        for (int j = 0; j < 4096; ++j) {
            float wj = tile[j];
            int jj = t0 + j;
            cnt += (wj > wn) || (wj == wn && jj < n);
        }
    }

    if (cnt < KCORR) {
        int r = side * KCORR + cnt;
        int sidx = bidx[(size_t)side * NPTS + n];
        if (sidx < 0) sidx = 0;
        int src_row = (side == 0) ? n : sidx;
        int tgt_row = (side == 0) ? sidx : n;

        float* out_srcP = out;                          // [2K,3]
        float* out_tgtP = out + 2 * KCORR * 3;          // [2K,3]
        float* out_srcF = out + 4 * KCORR * 3;          // [2K,64]
        float* out_tgtF = out_srcF + 2 * KCORR * CF;    // [2K,64]
        float* out_w    = out_tgtF + 2 * KCORR * CF;    // [2K]

        #pragma unroll
        for (int k = 0; k < 3; ++k) {
            out_srcP[(size_t)r * 3 + k] = src_points[(size_t)src_row * 3 + k];
            out_tgtP[(size_t)r * 3 + k] = tgt_points[(size_t)tgt_row * 3 + k];
        }
        const float4* sfr = (const float4*)(src_feats + (size_t)src_row * CF);
        const float4* tfr = (const float4*)(tgt_feats + (size_t)tgt_row * CF);
        float4* so = (float4*)(out_srcF + (size_t)r * CF);
        float4* to = (float4*)(out_tgtF + (size_t)r * CF);
        #pragma unroll
        for (int c = 0; c < CF / 4; ++c) { so[c] = sfr[c]; to[c] = tfr[c]; }
        out_w[r] = wn;
    }
}

// ---------------------------------------------------------------------------
extern "C" void kernel_launch(void* const* d_in, const int* in_sizes, int n_in,
                              void* d_out, int out_size, void* d_ws, size_t ws_size,
                              hipStream_t stream)
{
    const float* src_points = (const float*)d_in[0];
    const float* tgt_points = (const float*)d_in[1];
    const float* src_feats  = (const float*)d_in[2];
    const float* tgt_feats  = (const float*)d_in[3];
    float* out = (float*)d_out;
    (void)in_sizes; (void)n_in; (void)out_size; (void)ws_size;

    char* ws = (char*)d_ws;
    size_t off = 0;
    auto alloc = [&](size_t bytes) -> void* {
        void* p = ws + off;
        off += (bytes + 255) & ~(size_t)255;
        return p;
    };
    size_t nslots = (size_t)2 * NCH * NPTS;
    ushort_t* sfb = (ushort_t*)alloc(sizeof(ushort_t) * (size_t)NPTS * CF);
    ushort_t* tfb = (ushort_t*)alloc(sizeof(ushort_t) * (size_t)NPTS * CF);
    float* qq_src = (float*)alloc(sizeof(float) * NPTS);
    float* qq_tgt = (float*)alloc(sizeof(float) * NPTS);
    float* T      = (float*)alloc(sizeof(float) * 2 * NPTS);
    float* wgt    = (float*)alloc(sizeof(float) * 2 * NPTS);
    int*   bidx   = (int*)alloc(sizeof(int) * 2 * NPTS);
    float* pm1    = (float*)alloc(sizeof(float) * nslots);
    float* pm2    = (float*)alloc(sizeof(float) * nslots);
    float* pd0    = (float*)alloc(sizeof(float) * nslots);
    float* pd1    = (float*)alloc(sizeof(float) * nslots);
    int*   pi0    = (int*)alloc(sizeof(int) * nslots);
    int*   pi1    = (int*)alloc(sizeof(int) * nslots);

    conv_kernel<<<(NPTS * CF + 255) / 256, 256, 0, stream>>>(
        src_feats, tgt_feats, sfb, tfb);

    prep_kernel<<<(2 * NPTS + 255) / 256, 256, 0, stream>>>(
        src_feats, tgt_feats, qq_src, qq_tgt);

    screen_kernel<<<dim3(NPTS / 64, NCH, 2), 256, 0, stream>>>(
        sfb, tfb, qq_src, qq_tgt, pm1, pm2);

    combineT_kernel<<<(2 * NPTS + 255) / 256, 256, 0, stream>>>(
        pm1, pm2, T);

    refine_kernel<<<dim3(NPTS / 64, NCH, 2), 256, 0, stream>>>(
        sfb, tfb, src_feats, tgt_feats, qq_src, qq_tgt, T,
        pd0, pd1, pi0, pi1);

    merge_kernel<<<(2 * NPTS + 255) / 256, 256, 0, stream>>>(
        src_feats, tgt_feats, pd0, pd1, pi0, pi1, wgt, bidx);

    rank_gather_kernel<<<dim3(NPTS / 256, 2), 256, 0, stream>>>(
        wgt, bidx, src_points, tgt_points, src_feats, tgt_feats, out);
}